// Round 2
// baseline (9519.324 us; speedup 1.0000x reference)
//
#include <hip/hip_runtime.h>
#include <hip/hip_bf16.h>
#include <stdint.h>

#define B_ 2
#define T_ 2048
#define C_ 2048
#define NH 16
#define NKV 4
#define HD 128

static __device__ __forceinline__ float lo_bf(uint32_t u) {
  u <<= 16;
  return __builtin_bit_cast(float, u);
}
static __device__ __forceinline__ float hi_bf(uint32_t u) {
  u &= 0xffff0000u;
  return __builtin_bit_cast(float, u);
}

// C[M][N] = A[M][K] @ W[N][K]^T (+ optional bias), all fp32 row-major.
template<int BM, int BN, int BK, int TM, int TN, bool BIAS>
__global__ __launch_bounds__(256)
void gemm_bt(const float* __restrict__ A, const float* __restrict__ W,
             const float* __restrict__ bias, float* __restrict__ C,
             int M, int N, int K) {
  __shared__ float As[BM][BK + 1];
  __shared__ float Ws[BN][BK + 1];
  const int bm = blockIdx.y * BM, bn = blockIdx.x * BN;
  const int tid = threadIdx.x;
  const int tx = tid % (BN / TN), ty = tid / (BN / TN);
  float acc[TM][TN] = {};
  for (int k0 = 0; k0 < K; k0 += BK) {
    for (int i = tid; i < BM * BK; i += 256) {
      int r = i / BK, c = i % BK;
      As[r][c] = A[(size_t)(bm + r) * K + k0 + c];
    }
    for (int i = tid; i < BN * BK; i += 256) {
      int r = i / BK, c = i % BK;
      Ws[r][c] = W[(size_t)(bn + r) * K + k0 + c];
    }
    __syncthreads();
    #pragma unroll
    for (int kk = 0; kk < BK; ++kk) {
      float a[TM], w[TN];
      #pragma unroll
      for (int i = 0; i < TM; ++i) a[i] = As[ty * TM + i][kk];
      #pragma unroll
      for (int j = 0; j < TN; ++j) w[j] = Ws[tx * TN + j][kk];
      #pragma unroll
      for (int i = 0; i < TM; ++i)
        #pragma unroll
        for (int j = 0; j < TN; ++j) acc[i][j] += a[i] * w[j];
    }
    __syncthreads();
  }
  #pragma unroll
  for (int i = 0; i < TM; ++i) {
    #pragma unroll
    for (int j = 0; j < TN; ++j) {
      int r = bm + ty * TM + i, c = bn + tx * TN + j;
      float v = acc[i][j];
      if (BIAS) v += bias[c];
      C[(size_t)r * N + c] = v;
    }
  }
}

// Apply RoPE to q (from Yq) and k (first half of Ykv), scatter into
// Qr[b][h][t][d], Kr[b][g][t][d]; copy v into Vr[b][g][t][d].
__global__ __launch_bounds__(256)
void rope_scatter(const float* __restrict__ Yq, const float* __restrict__ Ykv,
                  const float* __restrict__ rf,
                  float* __restrict__ Qr, float* __restrict__ Kr,
                  float* __restrict__ Vr) {
  const int mrow = blockIdx.x;            // 0..B*T-1
  const int b = mrow >> 11, t = mrow & (T_ - 1);
  const float* rft = rf + (size_t)t * HD; // [64][2] cos/sin pairs
  // q: 1024 rotation pairs
  for (int pp = threadIdx.x; pp < 1024; pp += 256) {
    const int col = pp * 2;
    const int h = col >> 7, d = col & 127, p = d >> 1;
    const float c = rft[2 * p], s = rft[2 * p + 1];
    const float q0 = Yq[(size_t)mrow * 2048 + col];
    const float q1 = Yq[(size_t)mrow * 2048 + col + 1];
    float* dst = Qr + (((size_t)b * NH + h) * T_ + t) * HD + d;
    dst[0] = q0 * c - q1 * s;
    dst[1] = q0 * s + q1 * c;
  }
  // k: 256 rotation pairs
  for (int pp = threadIdx.x; pp < 256; pp += 256) {
    const int col = pp * 2;
    const int g = col >> 7, d = col & 127, p = d >> 1;
    const float c = rft[2 * p], s = rft[2 * p + 1];
    const float k0 = Ykv[(size_t)mrow * 1024 + col];
    const float k1 = Ykv[(size_t)mrow * 1024 + col + 1];
    float* dst = Kr + (((size_t)b * NKV + g) * T_ + t) * HD + d;
    dst[0] = k0 * c - k1 * s;
    dst[1] = k0 * s + k1 * c;
  }
  // v: plain copy
  for (int i = threadIdx.x; i < 512; i += 256) {
    const int g = i >> 7, d = i & 127;
    Vr[(((size_t)b * NKV + g) * T_ + t) * HD + d] =
        Ykv[(size_t)mrow * 1024 + 512 + i];
  }
}

// Causal GQA attention, online softmax. 2 threads per query row (each owns
// 64 of the 128 dims); q held packed-bf16 in registers; K/V from global
// (L2-resident: 1 MB per (b,kv)). Writes AT in [B][T][C] layout.
__global__ __launch_bounds__(128)
void attn_kernel(const float* __restrict__ Qr, const float* __restrict__ Kr,
                 const float* __restrict__ Vr, float* __restrict__ AT) {
  const int t0 = blockIdx.x * 64;
  const int bh = blockIdx.y;
  const int b = bh >> 4, h = bh & 15;
  const int kvi = h & (NKV - 1);  // reference uses jnp.tile -> h % N_KV
  const int tid = threadIdx.x;
  const int row = t0 + (tid >> 1);
  const int half = tid & 1;

  const float* qrow = Qr + (((size_t)b * NH + h) * T_ + row) * HD + half * 64;
  uint32_t qp[32];
  #pragma unroll
  for (int i = 0; i < 32; ++i) {
    float2 q2 = *(const float2*)(qrow + 2 * i);
    uint32_t u0 = __bfloat16_as_ushort(__float2bfloat16(q2.x));
    uint32_t u1 = __bfloat16_as_ushort(__float2bfloat16(q2.y));
    qp[i] = u0 | (u1 << 16);
  }
  const float* kbase = Kr + ((size_t)b * NKV + kvi) * T_ * HD + half * 64;
  const float* vbase = Vr + ((size_t)b * NKV + kvi) * T_ * HD + half * 64;

  float m = -3.0e38f, l = 0.f;
  float O[64] = {};
  const float scale = 0.08838834764831845f;  // 1/sqrt(128)
  const int send = t0 + 64;
  for (int s = 0; s < send; ++s) {
    const float* krow = kbase + (size_t)s * HD;
    float sc = 0.f;
    #pragma unroll
    for (int i = 0; i < 16; ++i) {
      float4 k4 = *(const float4*)(krow + 4 * i);
      sc += lo_bf(qp[2 * i]) * k4.x;
      sc += hi_bf(qp[2 * i]) * k4.y;
      sc += lo_bf(qp[2 * i + 1]) * k4.z;
      sc += hi_bf(qp[2 * i + 1]) * k4.w;
    }
    sc += __shfl_xor(sc, 1);   // combine the two 64-dim halves
    sc *= scale;
    if (s > row) sc = -3.0e38f;  // causal mask
    const float mn = fmaxf(m, sc);
    const float alpha = __expf(m - mn);
    const float p = __expf(sc - mn);
    l = l * alpha + p;
    const float* vrow = vbase + (size_t)s * HD;
    #pragma unroll
    for (int i = 0; i < 16; ++i) {
      float4 v4 = *(const float4*)(vrow + 4 * i);
      O[4 * i + 0] = O[4 * i + 0] * alpha + p * v4.x;
      O[4 * i + 1] = O[4 * i + 1] * alpha + p * v4.y;
      O[4 * i + 2] = O[4 * i + 2] * alpha + p * v4.z;
      O[4 * i + 3] = O[4 * i + 3] * alpha + p * v4.w;
    }
    m = mn;
  }
  const float inv = 1.0f / l;
  float* orow = AT + ((size_t)b * T_ + row) * C_ + h * HD + half * 64;
  #pragma unroll
  for (int i = 0; i < 16; ++i) {
    float4 o4 = make_float4(O[4 * i + 0] * inv, O[4 * i + 1] * inv,
                            O[4 * i + 2] * inv, O[4 * i + 3] * inv);
    *(float4*)(orow + 4 * i) = o4;
  }
}

extern "C" void kernel_launch(void* const* d_in, const int* in_sizes, int n_in,
                              void* d_out, int out_size, void* d_ws, size_t ws_size,
                              hipStream_t stream) {
  const float* x   = (const float*)d_in[0];
  const float* rf  = (const float*)d_in[1];
  const float* wq  = (const float*)d_in[2];
  const float* wkv = (const float*)d_in[3];
  const float* wo  = (const float*)d_in[4];
  const float* bo  = (const float*)d_in[5];
  float* out = (float*)d_out;

  const size_t M = (size_t)B_ * T_;  // 4096
  // Workspace layout (fp32). Yq is reused as AT after rope_scatter consumes it.
  float* Yq  = (float*)d_ws;               // 4096*2048  (later: AT)
  float* Ykv = Yq + M * 2048;              // 4096*1024
  float* Qr  = Ykv + M * 1024;             // 2*16*2048*128
  float* Kr  = Qr + (size_t)B_ * NH * T_ * HD;   // 2*4*2048*128
  float* Vr  = Kr + (size_t)B_ * NKV * T_ * HD;
  float* AT  = Yq;  // reuse

  dim3 blk(256);
  gemm_bt<64, 64, 16, 4, 4, false><<<dim3(2048 / 64, 4096 / 64), blk, 0, stream>>>(
      x, wq, nullptr, Yq, 4096, 2048, 2048);
  gemm_bt<64, 64, 16, 4, 4, false><<<dim3(1024 / 64, 4096 / 64), blk, 0, stream>>>(
      x, wkv, nullptr, Ykv, 4096, 1024, 2048);
  rope_scatter<<<dim3(4096), blk, 0, stream>>>(Yq, Ykv, rf, Qr, Kr, Vr);
  attn_kernel<<<dim3(T_ / 64, B_ * NH), dim3(128), 0, stream>>>(Qr, Kr, Vr, AT);
  gemm_bt<64, 64, 16, 4, 4, true><<<dim3(2048 / 64, 4096 / 64), blk, 0, stream>>>(
      AT, wo, bo, out, 4096, 2048, 2048);
}

// Round 5
// 2727.159 us; speedup vs baseline: 3.4906x; 3.4906x over previous
//
#include <hip/hip_runtime.h>
#include <hip/hip_bf16.h>
#include <stdint.h>

#define B_ 2
#define T_ 2048
#define C_ 2048
#define NH 16
#define NKV 4
#define HD 128

typedef __attribute__((ext_vector_type(4))) float f32x4;
typedef __attribute__((ext_vector_type(8))) short bf16x8;
typedef __attribute__((ext_vector_type(4))) int i32x4;

static __device__ __forceinline__ ushort f2bf(float f) {
  return __bfloat16_as_ushort(__float2bfloat16(f));
}
static __device__ __forceinline__ uint32_t pack_bf(float a, float b) {
  return (uint32_t)f2bf(a) | ((uint32_t)f2bf(b) << 16);
}

// C[M][N] = A[M][K] @ W[N][K]^T (+ optional bias), all fp32 row-major.
template<int BM, int BN, int BK, int TM, int TN, bool BIAS>
__global__ __launch_bounds__(256)
void gemm_bt(const float* __restrict__ A, const float* __restrict__ W,
             const float* __restrict__ bias, float* __restrict__ C,
             int M, int N, int K) {
  __shared__ float As[BM][BK + 1];
  __shared__ float Ws[BN][BK + 1];
  const int bm = blockIdx.y * BM, bn = blockIdx.x * BN;
  const int tid = threadIdx.x;
  const int tx = tid % (BN / TN), ty = tid / (BN / TN);
  float acc[TM][TN] = {};
  for (int k0 = 0; k0 < K; k0 += BK) {
    for (int i = tid; i < BM * BK; i += 256) {
      int r = i / BK, c = i % BK;
      As[r][c] = A[(size_t)(bm + r) * K + k0 + c];
    }
    for (int i = tid; i < BN * BK; i += 256) {
      int r = i / BK, c = i % BK;
      Ws[r][c] = W[(size_t)(bn + r) * K + k0 + c];
    }
    __syncthreads();
    #pragma unroll
    for (int kk = 0; kk < BK; ++kk) {
      float a[TM], w[TN];
      #pragma unroll
      for (int i = 0; i < TM; ++i) a[i] = As[ty * TM + i][kk];
      #pragma unroll
      for (int j = 0; j < TN; ++j) w[j] = Ws[tx * TN + j][kk];
      #pragma unroll
      for (int i = 0; i < TM; ++i)
        #pragma unroll
        for (int j = 0; j < TN; ++j) acc[i][j] += a[i] * w[j];
    }
    __syncthreads();
  }
  #pragma unroll
  for (int i = 0; i < TM; ++i) {
    #pragma unroll
    for (int j = 0; j < TN; ++j) {
      int r = bm + ty * TM + i, c = bn + tx * TN + j;
      float v = acc[i][j];
      if (BIAS) v += bias[c];
      C[(size_t)r * N + c] = v;
    }
  }
}

// RoPE + layout conversion to bf16:
//   Qb[b][h][t][d]  (rope applied, softmax scale folded in)
//   Kb[b][g][t][d]  (rope applied)
//   Vt[b][g][d][t]  (transposed for the PV A-fragment)
__global__ __launch_bounds__(256)
void prep_qkv(const float* __restrict__ Yq, const float* __restrict__ Ykv,
              const float* __restrict__ rf,
              ushort* __restrict__ Qb, ushort* __restrict__ Kb,
              ushort* __restrict__ Vt) {
  const int t0 = blockIdx.x * 16;
  const int b  = blockIdx.y;
  const int tid = threadIdx.x;
  const float scale = 0.08838834764831845f;  // 1/sqrt(128)
  __shared__ ushort vt_lds[HD][17];
  // Q: 16 rows x 1024 rotation pairs
  for (int i = tid; i < 16 * 1024; i += 256) {
    const int t = t0 + (i >> 10);
    const int col = (i & 1023) * 2;
    const int h = col >> 7, d = col & 127, p = d >> 1;
    const float c = rf[t * HD + 2 * p], s = rf[t * HD + 2 * p + 1];
    const size_t src = ((size_t)(b * T_) + t) * C_ + col;
    const float q0v = Yq[src], q1v = Yq[src + 1];
    ushort* dst = Qb + (((size_t)(b * NH + h)) * T_ + t) * HD + d;
    dst[0] = f2bf((q0v * c - q1v * s) * scale);
    dst[1] = f2bf((q0v * s + q1v * c) * scale);
  }
  // K: 16 rows x 256 rotation pairs
  for (int i = tid; i < 16 * 256; i += 256) {
    const int t = t0 + (i >> 8);
    const int col = (i & 255) * 2;
    const int g = col >> 7, d = col & 127, p = d >> 1;
    const float c = rf[t * HD + 2 * p], s = rf[t * HD + 2 * p + 1];
    const size_t src = ((size_t)(b * T_) + t) * 1024 + col;
    const float k0v = Ykv[src], k1v = Ykv[src + 1];
    ushort* dst = Kb + (((size_t)(b * NKV + g)) * T_ + t) * HD + d;
    dst[0] = f2bf(k0v * c - k1v * s);
    dst[1] = f2bf(k0v * s + k1v * c);
  }
  // V: transpose 16t x 128d -> Vt[d][t] via LDS, per kv-group
  for (int g = 0; g < NKV; ++g) {
    __syncthreads();
    for (int i = tid; i < 16 * HD; i += 256) {
      const int t = i >> 7, d = i & 127;
      vt_lds[d][t] = f2bf(Ykv[((size_t)(b * T_) + t0 + t) * 1024 + 512 + g * HD + d]);
    }
    __syncthreads();
    for (int i = tid; i < HD * 16; i += 256) {
      const int d = i >> 4, t = i & 15;
      Vt[(((size_t)(b * NKV + g)) * HD + d) * T_ + t0 + t] = vt_lds[d][t];
    }
  }
}

// MFMA flash attention (causal, GQA kv = h % 4).
// 4 waves/block; wave w owns q rows [q0+16w, q0+16w+16). KV tiles of 64.
// Swapped QK^T: S^T[s][q] = mfma(A=K, B=Q) so each lane owns ONE q column
// (lane&15) -> softmax reduce = 16 in-lane + shfl_xor(16,32).
// C/D layout (m89-verified): col = lane&15, row = (lane>>4)*4 + reg.
__global__ __launch_bounds__(256)
void flash_attn(const ushort* __restrict__ Qb, const ushort* __restrict__ Kb,
                const ushort* __restrict__ Vt, float* __restrict__ AT) {
  const int q0 = blockIdx.x * 64;
  const int bh = blockIdx.y;
  const int b = bh >> 4, h = bh & 15, g = h & (NKV - 1);
  const int wid = threadIdx.x >> 6;
  const int lane = threadIdx.x & 63;
  const int lg = lane >> 4;       // lane group 0..3
  const int qi = lane & 15;       // q column owned by this lane
  const int qrow = q0 + wid * 16 + qi;

  // Q B-fragment: B[k=d][n=q]: lane holds Q[qrow][32*dsl + lg*8 + j]
  const ushort* Qw = Qb + (((size_t)(b * NH + h)) * T_ + qrow) * HD;
  bf16x8 qf[4];
  #pragma unroll
  for (int dsl = 0; dsl < 4; ++dsl)
    qf[dsl] = *(const bf16x8*)(Qw + dsl * 32 + lg * 8);

  const ushort* Kbase = Kb + ((size_t)(b * NKV + g)) * T_ * HD;
  const ushort* Vbase = Vt + ((size_t)(b * NKV + g)) * HD * T_;

  float m = -3.0e38f, l = 0.f;
  f32x4 oacc[8];  // O^T: d = 16*dt + 4*lg + r, col q = qi
  #pragma unroll
  for (int i = 0; i < 8; ++i) oacc[i] = f32x4{0.f, 0.f, 0.f, 0.f};

  const int nkv = blockIdx.x + 1;
  for (int kv = 0; kv < nkv; ++kv) {
    const int sblk = kv * 64;
    // ---- S^T tiles: 4 x (16s x 16q), K-slices over d ----
    f32x4 sacc[4];
    #pragma unroll
    for (int st = 0; st < 4; ++st) sacc[st] = f32x4{0.f, 0.f, 0.f, 0.f};
    #pragma unroll
    for (int st = 0; st < 4; ++st) {
      const ushort* kr = Kbase + ((size_t)(sblk + st * 16 + qi)) * HD + lg * 8;
      #pragma unroll
      for (int dsl = 0; dsl < 4; ++dsl) {
        bf16x8 kf = *(const bf16x8*)(kr + dsl * 32);
        sacc[st] = __builtin_amdgcn_mfma_f32_16x16x32_bf16(kf, qf[dsl], sacc[st], 0, 0, 0);
      }
    }
    float sc[16];  // s = sblk + 16*st + 4*lg + r  (scale pre-folded into Q)
    #pragma unroll
    for (int st = 0; st < 4; ++st)
      #pragma unroll
      for (int r = 0; r < 4; ++r) sc[st * 4 + r] = sacc[st][r];
    // causal mask: only the diagonal block needs it (wave-uniform branch)
    if (sblk == q0) {
      #pragma unroll
      for (int st = 0; st < 4; ++st)
        #pragma unroll
        for (int r = 0; r < 4; ++r) {
          const int s = sblk + st * 16 + lg * 4 + r;
          if (s > qrow) sc[st * 4 + r] = -3.0e38f;
        }
    }
    // ---- online softmax (per q column) ----
    float mt = sc[0];
    #pragma unroll
    for (int i = 1; i < 16; ++i) mt = fmaxf(mt, sc[i]);
    mt = fmaxf(mt, __shfl_xor(mt, 16));
    mt = fmaxf(mt, __shfl_xor(mt, 32));
    const float mn = fmaxf(m, mt);
    const float alpha = __expf(m - mn);
    float ps = 0.f;
    #pragma unroll
    for (int i = 0; i < 16; ++i) { sc[i] = __expf(sc[i] - mn); ps += sc[i]; }
    ps += __shfl_xor(ps, 16);
    ps += __shfl_xor(ps, 32);
    l = l * alpha + ps;
    m = mn;
    #pragma unroll
    for (int i = 0; i < 8; ++i) oacc[i] *= alpha;
    // ---- pack P^T -> bf16 words; word[t][w] holds s-pair (16t+4lg+2w, +1) ----
    uint32_t wtw[4][2];
    #pragma unroll
    for (int t = 0; t < 4; ++t) {
      wtw[t][0] = pack_bf(sc[4 * t + 0], sc[4 * t + 1]);
      wtw[t][1] = pack_bf(sc[4 * t + 2], sc[4 * t + 3]);
    }
    // ---- rebuild PV B-fragment via ds_bpermute ----
    // need: lane(lg,qi) VGPR v of slice ss = s-pair (32ss + 8lg + 2v, +1) @ col qi
    // source: lane(g'=2*(lg&1)+(v>>1), qi), word[t = 2ss + (lg>>1)][w = v&1]
    bf16x8 pfrag[2];
    #pragma unroll
    for (int ss = 0; ss < 2; ++ss) {
      int w[4];
      #pragma unroll
      for (int v = 0; v < 4; ++v) {
        const int addr = ((2 * (lg & 1) + (v >> 1)) * 16 + qi) * 4;
        const int r0 = __builtin_amdgcn_ds_bpermute(addr, (int)wtw[2 * ss][v & 1]);
        const int r1 = __builtin_amdgcn_ds_bpermute(addr, (int)wtw[2 * ss + 1][v & 1]);
        w[v] = (lg & 2) ? r1 : r0;
      }
      i32x4 tmp = {w[0], w[1], w[2], w[3]};
      pfrag[ss] = __builtin_bit_cast(bf16x8, tmp);
    }
    // ---- PV: O^T[d][q] += V^T[d][s] P^T[s][q] ----
    #pragma unroll
    for (int dt = 0; dt < 8; ++dt) {
      const ushort* vr = Vbase + ((size_t)(dt * 16 + qi)) * T_ + sblk + lg * 8;
      const bf16x8 v0 = *(const bf16x8*)(vr);
      const bf16x8 v1 = *(const bf16x8*)(vr + 32);
      oacc[dt] = __builtin_amdgcn_mfma_f32_16x16x32_bf16(v0, pfrag[0], oacc[dt], 0, 0, 0);
      oacc[dt] = __builtin_amdgcn_mfma_f32_16x16x32_bf16(v1, pfrag[1], oacc[dt], 0, 0, 0);
    }
  }
  // ---- epilogue: O^T/l -> AT[b][t][h*128+d] ----
  const float inv = 1.0f / l;
  float* orow = AT + ((size_t)(b * T_) + qrow) * C_ + h * HD;
  #pragma unroll
  for (int dt = 0; dt < 8; ++dt) {
    f32x4 o = oacc[dt] * inv;
    *(f32x4*)(orow + dt * 16 + lg * 4) = o;
  }
}

extern "C" void kernel_launch(void* const* d_in, const int* in_sizes, int n_in,
                              void* d_out, int out_size, void* d_ws, size_t ws_size,
                              hipStream_t stream) {
  const float* x   = (const float*)d_in[0];
  const float* rf  = (const float*)d_in[1];
  const float* wq  = (const float*)d_in[2];
  const float* wkv = (const float*)d_in[3];
  const float* wo  = (const float*)d_in[4];
  const float* bo  = (const float*)d_in[5];
  float* out = (float*)d_out;

  const size_t M = (size_t)B_ * T_;  // 4096
  // Workspace: Yq fp32 (reused as AT), Ykv fp32, then bf16 Qb/Kb/Vt.
  float* Yq  = (float*)d_ws;                         // 4096*2048 f32
  float* Ykv = Yq + M * 2048;                        // 4096*1024 f32
  ushort* Qb = (ushort*)(Ykv + M * 1024);            // 2*16*2048*128 bf16
  ushort* Kb = Qb + (size_t)B_ * NH * T_ * HD;       // 2*4*2048*128 bf16
  ushort* Vt = Kb + (size_t)B_ * NKV * T_ * HD;      // 2*4*128*2048 bf16
  float* AT  = Yq;  // reuse

  dim3 blk(256);
  gemm_bt<64, 64, 16, 4, 4, false><<<dim3(2048 / 64, 4096 / 64), blk, 0, stream>>>(
      x, wq, nullptr, Yq, 4096, 2048, 2048);
  gemm_bt<64, 64, 16, 4, 4, false><<<dim3(1024 / 64, 4096 / 64), blk, 0, stream>>>(
      x, wkv, nullptr, Ykv, 4096, 1024, 2048);
  prep_qkv<<<dim3(T_ / 16, B_), blk, 0, stream>>>(Yq, Ykv, rf, Qb, Kb, Vt);
  flash_attn<<<dim3(T_ / 64, B_ * NH), blk, 0, stream>>>(Qb, Kb, Vt, AT);
  gemm_bt<64, 64, 16, 4, 4, true><<<dim3(2048 / 64, 4096 / 64), blk, 0, stream>>>(
      AT, wo, bo, out, 4096, 2048, 2048);
}

// Round 6
// 646.548 us; speedup vs baseline: 14.7233x; 4.2180x over previous
//
#include <hip/hip_runtime.h>
#include <hip/hip_bf16.h>
#include <stdint.h>

#define B_ 2
#define T_ 2048
#define C_ 2048
#define NH 16
#define NKV 4
#define HD 128

typedef __attribute__((ext_vector_type(4))) float f32x4;
typedef __attribute__((ext_vector_type(8))) short bf16x8;
typedef __attribute__((ext_vector_type(4))) int i32x4;

static __device__ __forceinline__ ushort f2bf(float f) {
  return __bfloat16_as_ushort(__float2bfloat16(f));
}
static __device__ __forceinline__ uint32_t pack_bf(float a, float b) {
  return (uint32_t)f2bf(a) | ((uint32_t)f2bf(b) << 16);
}

typedef __attribute__((address_space(1))) const void g1void;
typedef __attribute__((address_space(3))) void l3void;
static __device__ __forceinline__ void gload16(const void* g, void* l) {
  // async global->LDS, 16B per lane; LDS dest = wave-uniform base + lane*16
  __builtin_amdgcn_global_load_lds((g1void*)g, (l3void*)l, 16, 0, 0);
}

// ---- f32 -> bf16 cast, vectorized (float4 in, ushort4 out) ----
__global__ __launch_bounds__(256)
void cast_bf16(const float* __restrict__ in, ushort* __restrict__ out, int n4) {
  for (int i = blockIdx.x * 256 + threadIdx.x; i < n4; i += gridDim.x * 256) {
    float4 v = ((const float4*)in)[i];
    ushort4 o;
    o.x = f2bf(v.x); o.y = f2bf(v.y); o.z = f2bf(v.z); o.w = f2bf(v.w);
    ((ushort4*)out)[i] = o;
  }
}

// ---- bf16 MFMA GEMM (m97 structure): C[M][N] = A[M][K] @ W[N][K]^T (+bias) ----
// 128x128 tile, BK=64, 256 threads = 4 waves, each wave 64x64 (4x4 frags).
// Fragment layouts hardware-verified via flash_attn (round 5):
//   A/B input: lane&15 = m/n index, (lane>>4)*8+j = k;  C/D: col=lane&15, row=(lane>>4)*4+reg.
template<bool BIAS>
__global__ __launch_bounds__(256)
void gemm_mfma(const ushort* __restrict__ A, const ushort* __restrict__ W,
               const float* __restrict__ bias, float* __restrict__ C,
               int M, int N, int K) {
  __shared__ __align__(16) ushort As[128 * 64];
  __shared__ __align__(16) ushort Ws[128 * 64];
  const int tid = threadIdx.x;
  const int lane = tid & 63, wid = tid >> 6;
  const int wr = wid >> 1, wc = wid & 1;       // wave grid 2x2
  const int lr = lane & 15, lg = lane >> 4;
  const int bm = blockIdx.y * 128, bn = blockIdx.x * 128;

  f32x4 acc[4][4];
  #pragma unroll
  for (int mi = 0; mi < 4; ++mi)
    #pragma unroll
    for (int nj = 0; nj < 4; ++nj) acc[mi][nj] = f32x4{0.f, 0.f, 0.f, 0.f};

  const ushort* Ab = A + (size_t)bm * K;
  const ushort* Wb = W + (size_t)bn * K;

  for (int k0 = 0; k0 < K; k0 += 64) {
    // stage 128x64 bf16 tiles of A and W: 1024 x 16B chunks each, 4 issues/thread
    #pragma unroll
    for (int it = 0; it < 4; ++it) {
      const int cid = it * 256 + tid;
      const int r = cid >> 3, cc = (cid & 7) * 8;
      gload16(Ab + (size_t)r * K + k0 + cc, &As[cid * 8]);
      gload16(Wb + (size_t)r * K + k0 + cc, &Ws[cid * 8]);
    }
    __syncthreads();   // compiler emits vmcnt(0) drain before barrier
    #pragma unroll
    for (int ks = 0; ks < 2; ++ks) {
      bf16x8 af[4], bf[4];
      #pragma unroll
      for (int i = 0; i < 4; ++i) {
        af[i] = *(const bf16x8*)&As[(wr * 64 + i * 16 + lr) * 64 + ks * 32 + lg * 8];
        bf[i] = *(const bf16x8*)&Ws[(wc * 64 + i * 16 + lr) * 64 + ks * 32 + lg * 8];
      }
      #pragma unroll
      for (int mi = 0; mi < 4; ++mi)
        #pragma unroll
        for (int nj = 0; nj < 4; ++nj)
          acc[mi][nj] = __builtin_amdgcn_mfma_f32_16x16x32_bf16(af[mi], bf[nj], acc[mi][nj], 0, 0, 0);
    }
    __syncthreads();
  }
  // epilogue
  #pragma unroll
  for (int nj = 0; nj < 4; ++nj) {
    const int cn = bn + wc * 64 + nj * 16 + lr;
    const float bv = BIAS ? bias[cn] : 0.0f;
    #pragma unroll
    for (int mi = 0; mi < 4; ++mi) {
      const int rm = bm + wr * 64 + mi * 16 + lg * 4;
      #pragma unroll
      for (int r = 0; r < 4; ++r)
        C[(size_t)(rm + r) * N + cn] = acc[mi][nj][r] + bv;
    }
  }
}

// RoPE + layout conversion to bf16:
//   Qb[b][h][t][d]  (rope applied, softmax scale folded in)
//   Kb[b][g][t][d]  (rope applied)
//   Vt[b][g][d][t]  (transposed for the PV A-fragment)
__global__ __launch_bounds__(256)
void prep_qkv(const float* __restrict__ Yq, const float* __restrict__ Ykv,
              const float* __restrict__ rf,
              ushort* __restrict__ Qb, ushort* __restrict__ Kb,
              ushort* __restrict__ Vt) {
  const int t0 = blockIdx.x * 16;
  const int b  = blockIdx.y;
  const int tid = threadIdx.x;
  const float scale = 0.08838834764831845f;  // 1/sqrt(128)
  __shared__ ushort vt_lds[HD][17];
  for (int i = tid; i < 16 * 1024; i += 256) {
    const int t = t0 + (i >> 10);
    const int col = (i & 1023) * 2;
    const int h = col >> 7, d = col & 127, p = d >> 1;
    const float c = rf[t * HD + 2 * p], s = rf[t * HD + 2 * p + 1];
    const size_t src = ((size_t)(b * T_) + t) * C_ + col;
    const float q0v = Yq[src], q1v = Yq[src + 1];
    ushort* dst = Qb + (((size_t)(b * NH + h)) * T_ + t) * HD + d;
    dst[0] = f2bf((q0v * c - q1v * s) * scale);
    dst[1] = f2bf((q0v * s + q1v * c) * scale);
  }
  for (int i = tid; i < 16 * 256; i += 256) {
    const int t = t0 + (i >> 8);
    const int col = (i & 255) * 2;
    const int g = col >> 7, d = col & 127, p = d >> 1;
    const float c = rf[t * HD + 2 * p], s = rf[t * HD + 2 * p + 1];
    const size_t src = ((size_t)(b * T_) + t) * 1024 + col;
    const float k0v = Ykv[src], k1v = Ykv[src + 1];
    ushort* dst = Kb + (((size_t)(b * NKV + g)) * T_ + t) * HD + d;
    dst[0] = f2bf(k0v * c - k1v * s);
    dst[1] = f2bf(k0v * s + k1v * c);
  }
  for (int g = 0; g < NKV; ++g) {
    __syncthreads();
    for (int i = tid; i < 16 * HD; i += 256) {
      const int t = i >> 7, d = i & 127;
      vt_lds[d][t] = f2bf(Ykv[((size_t)(b * T_) + t0 + t) * 1024 + 512 + g * HD + d]);
    }
    __syncthreads();
    for (int i = tid; i < HD * 16; i += 256) {
      const int d = i >> 4, t = i & 15;
      Vt[(((size_t)(b * NKV + g)) * HD + d) * T_ + t0 + t] = vt_lds[d][t];
    }
  }
}

// MFMA flash attention (causal, GQA kv = h % 4). Output: bf16 ATb[b][t][h*128+d].
__global__ __launch_bounds__(256)
void flash_attn(const ushort* __restrict__ Qb, const ushort* __restrict__ Kb,
                const ushort* __restrict__ Vt, ushort* __restrict__ ATb) {
  const int q0 = blockIdx.x * 64;
  const int bh = blockIdx.y;
  const int b = bh >> 4, h = bh & 15, g = h & (NKV - 1);
  const int wid = threadIdx.x >> 6;
  const int lane = threadIdx.x & 63;
  const int lg = lane >> 4;
  const int qi = lane & 15;
  const int qrow = q0 + wid * 16 + qi;

  const ushort* Qw = Qb + (((size_t)(b * NH + h)) * T_ + qrow) * HD;
  bf16x8 qf[4];
  #pragma unroll
  for (int dsl = 0; dsl < 4; ++dsl)
    qf[dsl] = *(const bf16x8*)(Qw + dsl * 32 + lg * 8);

  const ushort* Kbase = Kb + ((size_t)(b * NKV + g)) * T_ * HD;
  const ushort* Vbase = Vt + ((size_t)(b * NKV + g)) * HD * T_;

  float m = -3.0e38f, l = 0.f;
  f32x4 oacc[8];
  #pragma unroll
  for (int i = 0; i < 8; ++i) oacc[i] = f32x4{0.f, 0.f, 0.f, 0.f};

  const int nkv = blockIdx.x + 1;
  for (int kv = 0; kv < nkv; ++kv) {
    const int sblk = kv * 64;
    f32x4 sacc[4];
    #pragma unroll
    for (int st = 0; st < 4; ++st) sacc[st] = f32x4{0.f, 0.f, 0.f, 0.f};
    #pragma unroll
    for (int st = 0; st < 4; ++st) {
      const ushort* kr = Kbase + ((size_t)(sblk + st * 16 + qi)) * HD + lg * 8;
      #pragma unroll
      for (int dsl = 0; dsl < 4; ++dsl) {
        bf16x8 kf = *(const bf16x8*)(kr + dsl * 32);
        sacc[st] = __builtin_amdgcn_mfma_f32_16x16x32_bf16(kf, qf[dsl], sacc[st], 0, 0, 0);
      }
    }
    float sc[16];
    #pragma unroll
    for (int st = 0; st < 4; ++st)
      #pragma unroll
      for (int r = 0; r < 4; ++r) sc[st * 4 + r] = sacc[st][r];
    if (sblk == q0) {
      #pragma unroll
      for (int st = 0; st < 4; ++st)
        #pragma unroll
        for (int r = 0; r < 4; ++r) {
          const int s = sblk + st * 16 + lg * 4 + r;
          if (s > qrow) sc[st * 4 + r] = -3.0e38f;
        }
    }
    float mt = sc[0];
    #pragma unroll
    for (int i = 1; i < 16; ++i) mt = fmaxf(mt, sc[i]);
    mt = fmaxf(mt, __shfl_xor(mt, 16));
    mt = fmaxf(mt, __shfl_xor(mt, 32));
    const float mn = fmaxf(m, mt);
    const float alpha = __expf(m - mn);
    float ps = 0.f;
    #pragma unroll
    for (int i = 0; i < 16; ++i) { sc[i] = __expf(sc[i] - mn); ps += sc[i]; }
    ps += __shfl_xor(ps, 16);
    ps += __shfl_xor(ps, 32);
    l = l * alpha + ps;
    m = mn;
    #pragma unroll
    for (int i = 0; i < 8; ++i) oacc[i] *= alpha;
    uint32_t wtw[4][2];
    #pragma unroll
    for (int t = 0; t < 4; ++t) {
      wtw[t][0] = pack_bf(sc[4 * t + 0], sc[4 * t + 1]);
      wtw[t][1] = pack_bf(sc[4 * t + 2], sc[4 * t + 3]);
    }
    bf16x8 pfrag[2];
    #pragma unroll
    for (int ss = 0; ss < 2; ++ss) {
      int w[4];
      #pragma unroll
      for (int v = 0; v < 4; ++v) {
        const int addr = ((2 * (lg & 1) + (v >> 1)) * 16 + qi) * 4;
        const int r0 = __builtin_amdgcn_ds_bpermute(addr, (int)wtw[2 * ss][v & 1]);
        const int r1 = __builtin_amdgcn_ds_bpermute(addr, (int)wtw[2 * ss + 1][v & 1]);
        w[v] = (lg & 2) ? r1 : r0;
      }
      i32x4 tmp = {w[0], w[1], w[2], w[3]};
      pfrag[ss] = __builtin_bit_cast(bf16x8, tmp);
    }
    #pragma unroll
    for (int dt = 0; dt < 8; ++dt) {
      const ushort* vr = Vbase + ((size_t)(dt * 16 + qi)) * T_ + sblk + lg * 8;
      const bf16x8 v0 = *(const bf16x8*)(vr);
      const bf16x8 v1 = *(const bf16x8*)(vr + 32);
      oacc[dt] = __builtin_amdgcn_mfma_f32_16x16x32_bf16(v0, pfrag[0], oacc[dt], 0, 0, 0);
      oacc[dt] = __builtin_amdgcn_mfma_f32_16x16x32_bf16(v1, pfrag[1], oacc[dt], 0, 0, 0);
    }
  }
  const float inv = 1.0f / l;
  ushort* orow = ATb + ((size_t)(b * T_) + qrow) * C_ + h * HD;
  #pragma unroll
  for (int dt = 0; dt < 8; ++dt) {
    f32x4 o = oacc[dt] * inv;
    ushort4 ob;
    ob.x = f2bf(o[0]); ob.y = f2bf(o[1]); ob.z = f2bf(o[2]); ob.w = f2bf(o[3]);
    *(ushort4*)(orow + dt * 16 + lg * 4) = ob;
  }
}

extern "C" void kernel_launch(void* const* d_in, const int* in_sizes, int n_in,
                              void* d_out, int out_size, void* d_ws, size_t ws_size,
                              hipStream_t stream) {
  const float* x   = (const float*)d_in[0];
  const float* rf  = (const float*)d_in[1];
  const float* wq  = (const float*)d_in[2];
  const float* wkv = (const float*)d_in[3];
  const float* wo  = (const float*)d_in[4];
  const float* bo  = (const float*)d_in[5];
  float* out = (float*)d_out;

  // Workspace layout (bytes). ATb aliases Yq (Yq dead after prep_qkv).
  uint8_t* w = (uint8_t*)d_ws;
  float*  Yq   = (float*)w;   w += (size_t)4096 * 2048 * 4;   // 32 MB
  float*  Ykv  = (float*)w;   w += (size_t)4096 * 1024 * 4;   // 16 MB
  ushort* Qb   = (ushort*)w;  w += (size_t)4096 * 2048 * 2;   // 16 MB
  ushort* Kb   = (ushort*)w;  w += (size_t)4096 * 512 * 2;    //  4 MB
  ushort* Vt   = (ushort*)w;  w += (size_t)4096 * 512 * 2;    //  4 MB
  ushort* xb   = (ushort*)w;  w += (size_t)4096 * 2048 * 2;   // 16 MB
  ushort* wqb  = (ushort*)w;  w += (size_t)2048 * 2048 * 2;   //  8 MB
  ushort* wkvb = (ushort*)w;  w += (size_t)1024 * 2048 * 2;   //  4 MB
  ushort* wob  = (ushort*)w;  w += (size_t)2048 * 2048 * 2;   //  8 MB
  ushort* ATb  = (ushort*)Yq;  // alias

  dim3 blk(256);
  cast_bf16<<<dim3(2048), blk, 0, stream>>>(x,   xb,   4096 * 2048 / 4);
  cast_bf16<<<dim3(2048), blk, 0, stream>>>(wq,  wqb,  2048 * 2048 / 4);
  cast_bf16<<<dim3(1024), blk, 0, stream>>>(wkv, wkvb, 1024 * 2048 / 4);
  cast_bf16<<<dim3(2048), blk, 0, stream>>>(wo,  wob,  2048 * 2048 / 4);

  gemm_mfma<false><<<dim3(16, 32), blk, 0, stream>>>(xb, wqb, nullptr, Yq, 4096, 2048, 2048);
  gemm_mfma<false><<<dim3(8, 32), blk, 0, stream>>>(xb, wkvb, nullptr, Ykv, 4096, 1024, 2048);
  prep_qkv<<<dim3(T_ / 16, B_), blk, 0, stream>>>(Yq, Ykv, rf, Qb, Kb, Vt);
  flash_attn<<<dim3(T_ / 64, B_ * NH), blk, 0, stream>>>(Qb, Kb, Vt, ATb);
  gemm_mfma<true><<<dim3(16, 32), blk, 0, stream>>>(ATb, wob, bo, out, 4096, 2048, 2048);
}

// Round 8
// 268.608 us; speedup vs baseline: 35.4395x; 2.4070x over previous
//
#include <hip/hip_runtime.h>
#include <hip/hip_bf16.h>
#include <stdint.h>

#define B_ 2
#define T_ 2048
#define C_ 2048
#define NH 16
#define NKV 4
#define HD 128

typedef __attribute__((ext_vector_type(4))) float f32x4;
typedef __attribute__((ext_vector_type(8))) short bf16x8;
typedef __attribute__((ext_vector_type(4))) int i32x4;

static __device__ __forceinline__ ushort f2bf(float f) {
  return __bfloat16_as_ushort(__float2bfloat16(f));
}
static __device__ __forceinline__ uint32_t pack_bf(float a, float b) {
  return (uint32_t)f2bf(a) | ((uint32_t)f2bf(b) << 16);
}

typedef __attribute__((address_space(1))) const void g1void;
typedef __attribute__((address_space(3))) void l3void;
static __device__ __forceinline__ void gload16(const void* g, void* l) {
  // async global->LDS, 16B per lane; LDS dest = wave-uniform base + lane*16
  __builtin_amdgcn_global_load_lds((g1void*)g, (l3void*)l, 16, 0, 0);
}

// ---- f32 -> bf16 cast, vectorized (float4 in, ushort4 out) ----
__global__ __launch_bounds__(256)
void cast_bf16(const float* __restrict__ in, ushort* __restrict__ out, int n4) {
  for (int i = blockIdx.x * 256 + threadIdx.x; i < n4; i += gridDim.x * 256) {
    float4 v = ((const float4*)in)[i];
    ushort4 o;
    o.x = f2bf(v.x); o.y = f2bf(v.y); o.z = f2bf(v.z); o.w = f2bf(v.w);
    ((ushort4*)out)[i] = o;
  }
}

// ---- bf16 MFMA GEMM (m97 structure): C[M][N] = A[M][K] @ W[N][K]^T (+bias) ----
template<bool BIAS>
__global__ __launch_bounds__(256)
void gemm_mfma(const ushort* __restrict__ A, const ushort* __restrict__ W,
               const float* __restrict__ bias, float* __restrict__ C,
               int M, int N, int K) {
  __shared__ __align__(16) ushort As[128 * 64];
  __shared__ __align__(16) ushort Ws[128 * 64];
  const int tid = threadIdx.x;
  const int lane = tid & 63, wid = tid >> 6;
  const int wr = wid >> 1, wc = wid & 1;       // wave grid 2x2
  const int lr = lane & 15, lg = lane >> 4;
  const int bm = blockIdx.y * 128, bn = blockIdx.x * 128;

  f32x4 acc[4][4];
  #pragma unroll
  for (int mi = 0; mi < 4; ++mi)
    #pragma unroll
    for (int nj = 0; nj < 4; ++nj) acc[mi][nj] = f32x4{0.f, 0.f, 0.f, 0.f};

  const ushort* Ab = A + (size_t)bm * K;
  const ushort* Wb = W + (size_t)bn * K;

  for (int k0 = 0; k0 < K; k0 += 64) {
    #pragma unroll
    for (int it = 0; it < 4; ++it) {
      const int cid = it * 256 + tid;
      const int r = cid >> 3, cc = (cid & 7) * 8;
      gload16(Ab + (size_t)r * K + k0 + cc, &As[cid * 8]);
      gload16(Wb + (size_t)r * K + k0 + cc, &Ws[cid * 8]);
    }
    __syncthreads();
    #pragma unroll
    for (int ks = 0; ks < 2; ++ks) {
      bf16x8 af[4], bf[4];
      #pragma unroll
      for (int i = 0; i < 4; ++i) {
        af[i] = *(const bf16x8*)&As[(wr * 64 + i * 16 + lr) * 64 + ks * 32 + lg * 8];
        bf[i] = *(const bf16x8*)&Ws[(wc * 64 + i * 16 + lr) * 64 + ks * 32 + lg * 8];
      }
      #pragma unroll
      for (int mi = 0; mi < 4; ++mi)
        #pragma unroll
        for (int nj = 0; nj < 4; ++nj)
          acc[mi][nj] = __builtin_amdgcn_mfma_f32_16x16x32_bf16(af[mi], bf[nj], acc[mi][nj], 0, 0, 0);
    }
    __syncthreads();
  }
  #pragma unroll
  for (int nj = 0; nj < 4; ++nj) {
    const int cn = bn + wc * 64 + nj * 16 + lr;
    const float bv = BIAS ? bias[cn] : 0.0f;
    #pragma unroll
    for (int mi = 0; mi < 4; ++mi) {
      const int rm = bm + wr * 64 + mi * 16 + lg * 4;
      #pragma unroll
      for (int r = 0; r < 4; ++r)
        C[(size_t)(rm + r) * N + cn] = acc[mi][nj][r] + bv;
    }
  }
}

// RoPE + layout conversion to bf16:
//   Qb[b][h][t][d]  (rope applied, softmax scale folded in)
//   Kb[b][g][t][d]  (rope applied)
//   Vt[b][g][d][t]  (transposed for the PV A-fragment)
__global__ __launch_bounds__(256)
void prep_qkv(const float* __restrict__ Yq, const float* __restrict__ Ykv,
              const float* __restrict__ rf,
              ushort* __restrict__ Qb, ushort* __restrict__ Kb,
              ushort* __restrict__ Vt) {
  const int t0 = blockIdx.x * 16;
  const int b  = blockIdx.y;
  const int tid = threadIdx.x;
  const float scale = 0.08838834764831845f;  // 1/sqrt(128)
  __shared__ ushort vt_lds[HD][17];
  for (int i = tid; i < 16 * 1024; i += 256) {
    const int t = t0 + (i >> 10);
    const int col = (i & 1023) * 2;
    const int h = col >> 7, d = col & 127, p = d >> 1;
    const float c = rf[t * HD + 2 * p], s = rf[t * HD + 2 * p + 1];
    const size_t src = ((size_t)(b * T_) + t) * C_ + col;
    const float q0v = Yq[src], q1v = Yq[src + 1];
    ushort* dst = Qb + (((size_t)(b * NH + h)) * T_ + t) * HD + d;
    dst[0] = f2bf((q0v * c - q1v * s) * scale);
    dst[1] = f2bf((q0v * s + q1v * c) * scale);
  }
  for (int i = tid; i < 16 * 256; i += 256) {
    const int t = t0 + (i >> 8);
    const int col = (i & 255) * 2;
    const int g = col >> 7, d = col & 127, p = d >> 1;
    const float c = rf[t * HD + 2 * p], s = rf[t * HD + 2 * p + 1];
    const size_t src = ((size_t)(b * T_) + t) * 1024 + col;
    const float k0v = Ykv[src], k1v = Ykv[src + 1];
    ushort* dst = Kb + (((size_t)(b * NKV + g)) * T_ + t) * HD + d;
    dst[0] = f2bf(k0v * c - k1v * s);
    dst[1] = f2bf(k0v * s + k1v * c);
  }
  for (int g = 0; g < NKV; ++g) {
    __syncthreads();
    for (int i = tid; i < 16 * HD; i += 256) {
      const int t = i >> 7, d = i & 127;
      vt_lds[d][t] = f2bf(Ykv[((size_t)(b * T_) + t0 + t) * 1024 + 512 + g * HD + d]);
    }
    __syncthreads();
    for (int i = tid; i < HD * 16; i += 256) {
      const int d = i >> 4, t = i & 15;
      Vt[(((size_t)(b * NKV + g)) * HD + d) * T_ + t0 + t] = vt_lds[d][t];
    }
  }
}

// MFMA flash attention, LDS-staged + double-buffered K/V shared by 8 waves.
// QBLK=128 (8 waves x 16 q-rows), KVBLK=64. Swapped QK^T, bpermute P-remap
// (hardware-verified round 5). K/V LDS tiles XOR-swizzled (rule #21:
// linear LDS dest via global_load_lds, pre-swizzled GLOBAL source, same
// XOR on the ds_read side): byte ^= ((row&7)<<4) -> 2-way conflicts (free).
__global__ __launch_bounds__(512, 4)
void flash_attn(const ushort* __restrict__ Qb, const ushort* __restrict__ Kb,
                const ushort* __restrict__ Vt, ushort* __restrict__ ATb) {
  __shared__ __align__(16) ushort Ks[2][64 * 128];   // [kv s][d], swizzled
  __shared__ __align__(16) ushort Vs[2][128 * 64];   // [d][kv s], swizzled

  // Makespan-balanced flat grid: pair block f (first dispatch round) with
  // f+256 (second round) so their strip lengths are complementary.
  const int f = blockIdx.x;
  const int second = f >> 8;
  const int fb = f & 255;
  const int bxl = fb & 15;
  const int bh = (fb >> 4) + (second << 4);   // 0..31
  const int qstrip = second ? bxl : (15 - bxl);
  const int q0 = qstrip * 128;

  const int b = bh >> 4, h = bh & 15, g = h & (NKV - 1);
  const int tid = threadIdx.x;
  const int wid = tid >> 6;
  const int lane = tid & 63;
  const int lg = lane >> 4;
  const int qi = lane & 15;
  const int qrow = q0 + wid * 16 + qi;
  const int swz = (qi & 7) << 4;   // read-side XOR (row&7 == qi&7, rows step by 16)

  const ushort* Qw = Qb + (((size_t)(b * NH + h)) * T_ + qrow) * HD;
  bf16x8 qf[4];
  #pragma unroll
  for (int dsl = 0; dsl < 4; ++dsl)
    qf[dsl] = *(const bf16x8*)(Qw + dsl * 32 + lg * 8);

  const ushort* Kbase = Kb + ((size_t)(b * NKV + g)) * T_ * HD;
  const ushort* Vbase = Vt + ((size_t)(b * NKV + g)) * HD * T_;

  float m = -3.0e38f, l = 0.f;
  f32x4 oacc[8];
  #pragma unroll
  for (int i = 0; i < 8; ++i) oacc[i] = f32x4{0.f, 0.f, 0.f, 0.f};

  const int nkv = 2 * qstrip + 2;

  // ---- staging: K tile 64x128 (row r: 256B), V tile 128x64 (row d: 128B) ----
  auto stage = [&](int buf, int sblk) {
    #pragma unroll
    for (int it = 0; it < 2; ++it) {
      const int c = it * 512 + tid;
      {  // K
        const int r = c >> 4, o = (c & 15) * 16;
        gload16(Kbase + (size_t)(sblk + r) * HD + ((o ^ ((r & 7) << 4)) >> 1),
                &Ks[buf][c * 8]);
      }
      {  // V
        const int d = c >> 3, o = (c & 7) * 16;
        gload16(Vbase + (size_t)d * T_ + sblk + ((o ^ ((d & 7) << 4)) >> 1),
                &Vs[buf][c * 8]);
      }
    }
  };

  auto compute = [&](int buf, int kv) {
    const int sblk = kv * 64;
    f32x4 sacc[4];
    #pragma unroll
    for (int st = 0; st < 4; ++st) sacc[st] = f32x4{0.f, 0.f, 0.f, 0.f};
    #pragma unroll
    for (int st = 0; st < 4; ++st) {
      const ushort* kr = &Ks[buf][(st * 16 + qi) * 128];
      #pragma unroll
      for (int dsl = 0; dsl < 4; ++dsl) {
        bf16x8 kf = *(const bf16x8*)(kr + (((dsl * 64 + lg * 16) ^ swz) >> 1));
        sacc[st] = __builtin_amdgcn_mfma_f32_16x16x32_bf16(kf, qf[dsl], sacc[st], 0, 0, 0);
      }
    }
    float sc[16];
    #pragma unroll
    for (int st = 0; st < 4; ++st)
      #pragma unroll
      for (int r = 0; r < 4; ++r) sc[st * 4 + r] = sacc[st][r];
    if (kv >= nkv - 2) {  // only the last two tiles can touch the diagonal
      #pragma unroll
      for (int st = 0; st < 4; ++st)
        #pragma unroll
        for (int r = 0; r < 4; ++r) {
          const int s = sblk + st * 16 + lg * 4 + r;
          if (s > qrow) sc[st * 4 + r] = -3.0e38f;
        }
    }
    float mt = sc[0];
    #pragma unroll
    for (int i = 1; i < 16; ++i) mt = fmaxf(mt, sc[i]);
    mt = fmaxf(mt, __shfl_xor(mt, 16));
    mt = fmaxf(mt, __shfl_xor(mt, 32));
    const float mn = fmaxf(m, mt);
    const float alpha = __expf(m - mn);
    float ps = 0.f;
    #pragma unroll
    for (int i = 0; i < 16; ++i) { sc[i] = __expf(sc[i] - mn); ps += sc[i]; }
    ps += __shfl_xor(ps, 16);
    ps += __shfl_xor(ps, 32);
    l = l * alpha + ps;
    m = mn;
    #pragma unroll
    for (int i = 0; i < 8; ++i) oacc[i] *= alpha;
    uint32_t wtw[4][2];
    #pragma unroll
    for (int t = 0; t < 4; ++t) {
      wtw[t][0] = pack_bf(sc[4 * t + 0], sc[4 * t + 1]);
      wtw[t][1] = pack_bf(sc[4 * t + 2], sc[4 * t + 3]);
    }
    bf16x8 pfrag[2];
    #pragma unroll
    for (int ss = 0; ss < 2; ++ss) {
      int w[4];
      #pragma unroll
      for (int v = 0; v < 4; ++v) {
        const int addr = ((2 * (lg & 1) + (v >> 1)) * 16 + qi) * 4;
        const int r0 = __builtin_amdgcn_ds_bpermute(addr, (int)wtw[2 * ss][v & 1]);
        const int r1 = __builtin_amdgcn_ds_bpermute(addr, (int)wtw[2 * ss + 1][v & 1]);
        w[v] = (lg & 2) ? r1 : r0;
      }
      i32x4 tmp = {w[0], w[1], w[2], w[3]};
      pfrag[ss] = __builtin_bit_cast(bf16x8, tmp);
    }
    #pragma unroll
    for (int dt = 0; dt < 8; ++dt) {
      const ushort* vr = &Vs[buf][(dt * 16 + qi) * 64];
      const bf16x8 v0 = *(const bf16x8*)(vr + (((lg * 16) ^ swz) >> 1));
      const bf16x8 v1 = *(const bf16x8*)(vr + (((64 + lg * 16) ^ swz) >> 1));
      oacc[dt] = __builtin_amdgcn_mfma_f32_16x16x32_bf16(v0, pfrag[0], oacc[dt], 0, 0, 0);
      oacc[dt] = __builtin_amdgcn_mfma_f32_16x16x32_bf16(v1, pfrag[1], oacc[dt], 0, 0, 0);
    }
  };

  // ---- double-buffered main loop: one barrier per tile ----
  stage(0, 0);
  __syncthreads();
  for (int kv = 0; kv < nkv - 1; ++kv) {
    stage((kv + 1) & 1, (kv + 1) * 64);  // prefetch next tile
    compute(kv & 1, kv);                 // compute current
    __syncthreads();                     // drain prefetch + protect reuse
  }
  compute((nkv - 1) & 1, nkv - 1);

  const float inv = 1.0f / l;
  ushort* orow = ATb + ((size_t)(b * T_) + qrow) * C_ + h * HD;
  #pragma unroll
  for (int dt = 0; dt < 8; ++dt) {
    f32x4 o = oacc[dt] * inv;
    ushort4 ob;
    ob.x = f2bf(o[0]); ob.y = f2bf(o[1]); ob.z = f2bf(o[2]); ob.w = f2bf(o[3]);
    *(ushort4*)(orow + dt * 16 + lg * 4) = ob;
  }
}

extern "C" void kernel_launch(void* const* d_in, const int* in_sizes, int n_in,
                              void* d_out, int out_size, void* d_ws, size_t ws_size,
                              hipStream_t stream) {
  const float* x   = (const float*)d_in[0];
  const float* rf  = (const float*)d_in[1];
  const float* wq  = (const float*)d_in[2];
  const float* wkv = (const float*)d_in[3];
  const float* wo  = (const float*)d_in[4];
  const float* bo  = (const float*)d_in[5];
  float* out = (float*)d_out;

  uint8_t* w = (uint8_t*)d_ws;
  float*  Yq   = (float*)w;   w += (size_t)4096 * 2048 * 4;   // 32 MB
  float*  Ykv  = (float*)w;   w += (size_t)4096 * 1024 * 4;   // 16 MB
  ushort* Qb   = (ushort*)w;  w += (size_t)4096 * 2048 * 2;   // 16 MB
  ushort* Kb   = (ushort*)w;  w += (size_t)4096 * 512 * 2;    //  4 MB
  ushort* Vt   = (ushort*)w;  w += (size_t)4096 * 512 * 2;    //  4 MB
  ushort* xb   = (ushort*)w;  w += (size_t)4096 * 2048 * 2;   // 16 MB
  ushort* wqb  = (ushort*)w;  w += (size_t)2048 * 2048 * 2;   //  8 MB
  ushort* wkvb = (ushort*)w;  w += (size_t)1024 * 2048 * 2;   //  4 MB
  ushort* wob  = (ushort*)w;  w += (size_t)2048 * 2048 * 2;   //  8 MB
  ushort* ATb  = (ushort*)Yq;  // alias (Yq dead after prep_qkv)

  dim3 blk(256);
  cast_bf16<<<dim3(2048), blk, 0, stream>>>(x,   xb,   4096 * 2048 / 4);
  cast_bf16<<<dim3(2048), blk, 0, stream>>>(wq,  wqb,  2048 * 2048 / 4);
  cast_bf16<<<dim3(1024), blk, 0, stream>>>(wkv, wkvb, 1024 * 2048 / 4);
  cast_bf16<<<dim3(2048), blk, 0, stream>>>(wo,  wob,  2048 * 2048 / 4);

  gemm_mfma<false><<<dim3(16, 32), blk, 0, stream>>>(xb, wqb, nullptr, Yq, 4096, 2048, 2048);
  gemm_mfma<false><<<dim3(8, 32), blk, 0, stream>>>(xb, wkvb, nullptr, Ykv, 4096, 1024, 2048);
  prep_qkv<<<dim3(T_ / 16, B_), blk, 0, stream>>>(Yq, Ykv, rf, Qb, Kb, Vt);
  flash_attn<<<dim3(512), dim3(512), 0, stream>>>(Qb, Kb, Vt, ATb);
  gemm_mfma<true><<<dim3(16, 32), blk, 0, stream>>>(ATb, wob, bo, out, 4096, 2048, 2048);
}

// Round 9
// 258.746 us; speedup vs baseline: 36.7902x; 1.0381x over previous
//
#include <hip/hip_runtime.h>
#include <hip/hip_bf16.h>
#include <stdint.h>

#define B_ 2
#define T_ 2048
#define C_ 2048
#define NH 16
#define NKV 4
#define HD 128

typedef __attribute__((ext_vector_type(4))) float f32x4;
typedef __attribute__((ext_vector_type(8))) short bf16x8;
typedef __attribute__((ext_vector_type(4))) int i32x4;

static __device__ __forceinline__ ushort f2bf(float f) {
  return __bfloat16_as_ushort(__float2bfloat16(f));
}
static __device__ __forceinline__ uint32_t pack_bf(float a, float b) {
  return (uint32_t)f2bf(a) | ((uint32_t)f2bf(b) << 16);
}

typedef __attribute__((address_space(1))) const void g1void;
typedef __attribute__((address_space(3))) void l3void;
static __device__ __forceinline__ void gload16(const void* g, void* l) {
  // async global->LDS, 16B per lane; LDS dest = wave-uniform base + lane*16
  __builtin_amdgcn_global_load_lds((g1void*)g, (l3void*)l, 16, 0, 0);
}

// ---- f32 -> bf16 cast, vectorized (float4 in, ushort4 out) ----
__global__ __launch_bounds__(256)
void cast_bf16(const float* __restrict__ in, ushort* __restrict__ out, int n4) {
  for (int i = blockIdx.x * 256 + threadIdx.x; i < n4; i += gridDim.x * 256) {
    float4 v = ((const float4*)in)[i];
    ushort4 o;
    o.x = f2bf(v.x); o.y = f2bf(v.y); o.z = f2bf(v.z); o.w = f2bf(v.w);
    ((ushort4*)out)[i] = o;
  }
}

// ---- bf16 MFMA GEMM, fused epilogues ----
// MODE 0: C = A@W^T + bias, f32 out (O-projection).
// MODE 1: RoPE(A@W^T)*scale -> bf16 Qb[b][h][t][d].
// MODE 2: cols<512: RoPE -> bf16 Kb[b][g][t][d]; cols>=512: bf16 Vtmp[row][c-512].
// RoPE pair element obtained via __shfl_xor(v,1): lane parity == column parity.
template<int MODE>
__global__ __launch_bounds__(256)
void gemm_mfma(const ushort* __restrict__ A, const ushort* __restrict__ W,
               const float* __restrict__ bias, float* __restrict__ Cf,
               ushort* __restrict__ O1, ushort* __restrict__ O2,
               const float* __restrict__ rf, int M, int N, int K) {
  __shared__ __align__(16) ushort As[128 * 64];
  __shared__ __align__(16) ushort Ws[128 * 64];
  const int tid = threadIdx.x;
  const int lane = tid & 63, wid = tid >> 6;
  const int wr = wid >> 1, wc = wid & 1;       // wave grid 2x2
  const int lr = lane & 15, lg = lane >> 4;
  const int bm = blockIdx.y * 128, bn = blockIdx.x * 128;

  f32x4 acc[4][4];
  #pragma unroll
  for (int mi = 0; mi < 4; ++mi)
    #pragma unroll
    for (int nj = 0; nj < 4; ++nj) acc[mi][nj] = f32x4{0.f, 0.f, 0.f, 0.f};

  const ushort* Ab = A + (size_t)bm * K;
  const ushort* Wb = W + (size_t)bn * K;

  for (int k0 = 0; k0 < K; k0 += 64) {
    #pragma unroll
    for (int it = 0; it < 4; ++it) {
      const int cid = it * 256 + tid;
      const int r = cid >> 3, cc = (cid & 7) * 8;
      gload16(Ab + (size_t)r * K + k0 + cc, &As[cid * 8]);
      gload16(Wb + (size_t)r * K + k0 + cc, &Ws[cid * 8]);
    }
    __syncthreads();
    #pragma unroll
    for (int ks = 0; ks < 2; ++ks) {
      bf16x8 af[4], bf[4];
      #pragma unroll
      for (int i = 0; i < 4; ++i) {
        af[i] = *(const bf16x8*)&As[(wr * 64 + i * 16 + lr) * 64 + ks * 32 + lg * 8];
        bf[i] = *(const bf16x8*)&Ws[(wc * 64 + i * 16 + lr) * 64 + ks * 32 + lg * 8];
      }
      #pragma unroll
      for (int mi = 0; mi < 4; ++mi)
        #pragma unroll
        for (int nj = 0; nj < 4; ++nj)
          acc[mi][nj] = __builtin_amdgcn_mfma_f32_16x16x32_bf16(af[mi], bf[nj], acc[mi][nj], 0, 0, 0);
    }
    __syncthreads();
  }
  // ---- fused epilogue ----
  #pragma unroll
  for (int nj = 0; nj < 4; ++nj) {
    const int cn = bn + wc * 64 + nj * 16 + lr;
    const float bv = (MODE == 0) ? bias[cn] : 0.0f;
    #pragma unroll
    for (int mi = 0; mi < 4; ++mi) {
      const int rm = bm + wr * 64 + mi * 16 + lg * 4;
      #pragma unroll
      for (int r = 0; r < 4; ++r) {
        const int row = rm + r;
        const float v = acc[mi][nj][r];
        if (MODE == 0) {
          Cf[(size_t)row * N + cn] = v + bv;
        } else {
          const int t = row & (T_ - 1), bb = row >> 11;
          if (MODE == 2 && cn >= 512) {
            O2[(size_t)row * 512 + (cn - 512)] = f2bf(v);
          } else {
            const int d = cn & 127;
            const float2 cs = *(const float2*)&rf[t * HD + (d & ~1)];
            const float p = __shfl_xor(v, 1);
            float o = (cn & 1) ? (p * cs.y + v * cs.x) : (v * cs.x - p * cs.y);
            if (MODE == 1) {
              o *= 0.08838834764831845f;  // 1/sqrt(128)
              O1[(((size_t)(bb * NH + (cn >> 7))) * T_ + t) * HD + d] = f2bf(o);
            } else {
              O1[(((size_t)(bb * NKV + (cn >> 7))) * T_ + t) * HD + d] = f2bf(o);
            }
          }
        }
      }
    }
  }
}

// ---- Vtmp[row][c] (bf16, row=b*2048+t, c=g*128+d) -> Vt[b][g][d][t] ----
__global__ __launch_bounds__(256)
void v_transpose(const ushort* __restrict__ Vtmp, ushort* __restrict__ Vt) {
  __shared__ ushort tl[64][65];
  const int bt = blockIdx.x;           // t tile (64 rows), 0..63
  const int bc = blockIdx.y;           // col tile (64 cols), 0..7
  const int tid = threadIdx.x;
  for (int i = tid; i < 64 * 16; i += 256) {
    const int tr = i >> 4, c4 = i & 15;
    ushort4 v = *(const ushort4*)&Vtmp[(size_t)(bt * 64 + tr) * 512 + bc * 64 + c4 * 4];
    tl[tr][c4 * 4 + 0] = v.x; tl[tr][c4 * 4 + 1] = v.y;
    tl[tr][c4 * 4 + 2] = v.z; tl[tr][c4 * 4 + 3] = v.w;
  }
  __syncthreads();
  const int b = bt >> 5, tloc0 = (bt * 64) & (T_ - 1);
  const int g = (bc * 64) >> 7, dbase = (bc * 64) & 127;
  for (int i = tid; i < 64 * 16; i += 256) {
    const int dr = i >> 4, t4 = i & 15;
    ushort4 v;
    v.x = tl[t4 * 4 + 0][dr]; v.y = tl[t4 * 4 + 1][dr];
    v.z = tl[t4 * 4 + 2][dr]; v.w = tl[t4 * 4 + 3][dr];
    *(ushort4*)&Vt[(((size_t)(b * NKV + g)) * HD + dbase + dr) * T_ + tloc0 + t4 * 4] = v;
  }
}

// MFMA flash attention, LDS-staged + double-buffered K/V shared by 8 waves.
// QBLK=128 (8 waves x 16 q-rows), KVBLK=64. Swapped QK^T, bpermute P-remap
// (hardware-verified round 5). K/V LDS tiles XOR-swizzled both-sides (rule #21).
__global__ __launch_bounds__(512, 4)
void flash_attn(const ushort* __restrict__ Qb, const ushort* __restrict__ Kb,
                const ushort* __restrict__ Vt, ushort* __restrict__ ATb) {
  __shared__ __align__(16) ushort Ks[2][64 * 128];   // [kv s][d], swizzled
  __shared__ __align__(16) ushort Vs[2][128 * 64];   // [d][kv s], swizzled

  // Makespan-balanced flat grid: pair block f (first dispatch round) with
  // f+256 (second round) so their strip lengths are complementary.
  const int f = blockIdx.x;
  const int second = f >> 8;
  const int fb = f & 255;
  const int bxl = fb & 15;
  const int bh = (fb >> 4) + (second << 4);   // 0..31
  const int qstrip = second ? bxl : (15 - bxl);
  const int q0 = qstrip * 128;

  const int b = bh >> 4, h = bh & 15, g = h & (NKV - 1);
  const int tid = threadIdx.x;
  const int wid = tid >> 6;
  const int lane = tid & 63;
  const int lg = lane >> 4;
  const int qi = lane & 15;
  const int qrow = q0 + wid * 16 + qi;
  const int swz = (qi & 7) << 4;   // read-side XOR

  const ushort* Qw = Qb + (((size_t)(b * NH + h)) * T_ + qrow) * HD;
  bf16x8 qf[4];
  #pragma unroll
  for (int dsl = 0; dsl < 4; ++dsl)
    qf[dsl] = *(const bf16x8*)(Qw + dsl * 32 + lg * 8);

  const ushort* Kbase = Kb + ((size_t)(b * NKV + g)) * T_ * HD;
  const ushort* Vbase = Vt + ((size_t)(b * NKV + g)) * HD * T_;

  float m = -3.0e38f, l = 0.f;
  f32x4 oacc[8];
  #pragma unroll
  for (int i = 0; i < 8; ++i) oacc[i] = f32x4{0.f, 0.f, 0.f, 0.f};

  const int nkv = 2 * qstrip + 2;

  auto stage = [&](int buf, int sblk) {
    #pragma unroll
    for (int it = 0; it < 2; ++it) {
      const int c = it * 512 + tid;
      {  // K
        const int r = c >> 4, o = (c & 15) * 16;
        gload16(Kbase + (size_t)(sblk + r) * HD + ((o ^ ((r & 7) << 4)) >> 1),
                &Ks[buf][c * 8]);
      }
      {  // V
        const int d = c >> 3, o = (c & 7) * 16;
        gload16(Vbase + (size_t)d * T_ + sblk + ((o ^ ((d & 7) << 4)) >> 1),
                &Vs[buf][c * 8]);
      }
    }
  };

  auto compute = [&](int buf, int kv) {
    const int sblk = kv * 64;
    f32x4 sacc[4];
    #pragma unroll
    for (int st = 0; st < 4; ++st) sacc[st] = f32x4{0.f, 0.f, 0.f, 0.f};
    __builtin_amdgcn_s_setprio(1);
    #pragma unroll
    for (int st = 0; st < 4; ++st) {
      const ushort* kr = &Ks[buf][(st * 16 + qi) * 128];
      #pragma unroll
      for (int dsl = 0; dsl < 4; ++dsl) {
        bf16x8 kf = *(const bf16x8*)(kr + (((dsl * 64 + lg * 16) ^ swz) >> 1));
        sacc[st] = __builtin_amdgcn_mfma_f32_16x16x32_bf16(kf, qf[dsl], sacc[st], 0, 0, 0);
      }
    }
    __builtin_amdgcn_s_setprio(0);
    float sc[16];
    #pragma unroll
    for (int st = 0; st < 4; ++st)
      #pragma unroll
      for (int r = 0; r < 4; ++r) sc[st * 4 + r] = sacc[st][r];
    if (kv >= nkv - 2) {  // only the last two tiles can touch the diagonal
      #pragma unroll
      for (int st = 0; st < 4; ++st)
        #pragma unroll
        for (int r = 0; r < 4; ++r) {
          const int s = sblk + st * 16 + lg * 4 + r;
          if (s > qrow) sc[st * 4 + r] = -3.0e38f;
        }
    }
    float mt = sc[0];
    #pragma unroll
    for (int i = 1; i < 16; ++i) mt = fmaxf(mt, sc[i]);
    mt = fmaxf(mt, __shfl_xor(mt, 16));
    mt = fmaxf(mt, __shfl_xor(mt, 32));
    const float mn = fmaxf(m, mt);
    const float alpha = __expf(m - mn);
    float ps = 0.f;
    #pragma unroll
    for (int i = 0; i < 16; ++i) { sc[i] = __expf(sc[i] - mn); ps += sc[i]; }
    ps += __shfl_xor(ps, 16);
    ps += __shfl_xor(ps, 32);
    l = l * alpha + ps;
    m = mn;
    #pragma unroll
    for (int i = 0; i < 8; ++i) oacc[i] *= alpha;
    uint32_t wtw[4][2];
    #pragma unroll
    for (int t = 0; t < 4; ++t) {
      wtw[t][0] = pack_bf(sc[4 * t + 0], sc[4 * t + 1]);
      wtw[t][1] = pack_bf(sc[4 * t + 2], sc[4 * t + 3]);
    }
    bf16x8 pfrag[2];
    #pragma unroll
    for (int ss = 0; ss < 2; ++ss) {
      int w[4];
      #pragma unroll
      for (int v = 0; v < 4; ++v) {
        const int addr = ((2 * (lg & 1) + (v >> 1)) * 16 + qi) * 4;
        const int r0 = __builtin_amdgcn_ds_bpermute(addr, (int)wtw[2 * ss][v & 1]);
        const int r1 = __builtin_amdgcn_ds_bpermute(addr, (int)wtw[2 * ss + 1][v & 1]);
        w[v] = (lg & 2) ? r1 : r0;
      }
      i32x4 tmp = {w[0], w[1], w[2], w[3]};
      pfrag[ss] = __builtin_bit_cast(bf16x8, tmp);
    }
    __builtin_amdgcn_s_setprio(1);
    #pragma unroll
    for (int dt = 0; dt < 8; ++dt) {
      const ushort* vr = &Vs[buf][(dt * 16 + qi) * 64];
      const bf16x8 v0 = *(const bf16x8*)(vr + (((lg * 16) ^ swz) >> 1));
      const bf16x8 v1 = *(const bf16x8*)(vr + (((64 + lg * 16) ^ swz) >> 1));
      oacc[dt] = __builtin_amdgcn_mfma_f32_16x16x32_bf16(v0, pfrag[0], oacc[dt], 0, 0, 0);
      oacc[dt] = __builtin_amdgcn_mfma_f32_16x16x32_bf16(v1, pfrag[1], oacc[dt], 0, 0, 0);
    }
    __builtin_amdgcn_s_setprio(0);
  };

  stage(0, 0);
  __syncthreads();
  for (int kv = 0; kv < nkv - 1; ++kv) {
    stage((kv + 1) & 1, (kv + 1) * 64);  // prefetch next tile
    compute(kv & 1, kv);                 // compute current
    __syncthreads();                     // drain prefetch + protect reuse
  }
  compute((nkv - 1) & 1, nkv - 1);

  const float inv = 1.0f / l;
  ushort* orow = ATb + ((size_t)(b * T_) + qrow) * C_ + h * HD;
  #pragma unroll
  for (int dt = 0; dt < 8; ++dt) {
    f32x4 o = oacc[dt] * inv;
    ushort4 ob;
    ob.x = f2bf(o[0]); ob.y = f2bf(o[1]); ob.z = f2bf(o[2]); ob.w = f2bf(o[3]);
    *(ushort4*)(orow + dt * 16 + lg * 4) = ob;
  }
}

extern "C" void kernel_launch(void* const* d_in, const int* in_sizes, int n_in,
                              void* d_out, int out_size, void* d_ws, size_t ws_size,
                              hipStream_t stream) {
  const float* x   = (const float*)d_in[0];
  const float* rf  = (const float*)d_in[1];
  const float* wq  = (const float*)d_in[2];
  const float* wkv = (const float*)d_in[3];
  const float* wo  = (const float*)d_in[4];
  const float* bo  = (const float*)d_in[5];
  float* out = (float*)d_out;

  uint8_t* w = (uint8_t*)d_ws;
  ushort* ATb  = (ushort*)w;  w += (size_t)4096 * 2048 * 2;   // 16 MB
  ushort* Vtmp = (ushort*)w;  w += (size_t)4096 * 512 * 2;    //  4 MB
  ushort* Qb   = (ushort*)w;  w += (size_t)4096 * 2048 * 2;   // 16 MB
  ushort* Kb   = (ushort*)w;  w += (size_t)4096 * 512 * 2;    //  4 MB
  ushort* Vt   = (ushort*)w;  w += (size_t)4096 * 512 * 2;    //  4 MB
  ushort* xb   = (ushort*)w;  w += (size_t)4096 * 2048 * 2;   // 16 MB
  ushort* wqb  = (ushort*)w;  w += (size_t)2048 * 2048 * 2;   //  8 MB
  ushort* wkvb = (ushort*)w;  w += (size_t)1024 * 2048 * 2;   //  4 MB
  ushort* wob  = (ushort*)w;  w += (size_t)2048 * 2048 * 2;   //  8 MB

  dim3 blk(256);
  cast_bf16<<<dim3(2048), blk, 0, stream>>>(x,   xb,   4096 * 2048 / 4);
  cast_bf16<<<dim3(2048), blk, 0, stream>>>(wq,  wqb,  2048 * 2048 / 4);
  cast_bf16<<<dim3(1024), blk, 0, stream>>>(wkv, wkvb, 1024 * 2048 / 4);
  cast_bf16<<<dim3(2048), blk, 0, stream>>>(wo,  wob,  2048 * 2048 / 4);

  // Q projection + RoPE -> Qb
  gemm_mfma<1><<<dim3(16, 32), blk, 0, stream>>>(xb, wqb, nullptr, nullptr,
                                                 Qb, nullptr, rf, 4096, 2048, 2048);
  // KV projection: K + RoPE -> Kb, V -> Vtmp
  gemm_mfma<2><<<dim3(8, 32), blk, 0, stream>>>(xb, wkvb, nullptr, nullptr,
                                                Kb, Vtmp, rf, 4096, 1024, 2048);
  v_transpose<<<dim3(64, 8), blk, 0, stream>>>(Vtmp, Vt);
  flash_attn<<<dim3(512), dim3(512), 0, stream>>>(Qb, Kb, Vt, ATb);
  // Output projection + bias -> out (f32)
  gemm_mfma<0><<<dim3(16, 32), blk, 0, stream>>>(ATb, wob, bo, out,
                                                 nullptr, nullptr, nullptr, 4096, 2048, 2048);
}